// Round 10
// baseline (534.938 us; speedup 1.0000x reference)
//
#include <hip/hip_runtime.h>

#define N_NODES 50000
#define E_EDGES 800000
#define E_TOT   (E_EDGES + N_NODES)
#define F_INDIM 128
#define NHEAD   4
#define CDIM    64
#define HC      256
#define NGRAPH  512
#define NCLS    10
#define NEG_SLOPE 0.2f
#define AGG_BLOCKS 2048
#define XCHUNKS (N_NODES * F_INDIM / 8)

typedef __attribute__((ext_vector_type(8))) _Float16 f16x8;
typedef __attribute__((ext_vector_type(8))) unsigned short ushort8;
typedef __attribute__((ext_vector_type(4))) float f32x4;

__device__ inline float leakyf(float x) { return x > 0.f ? x : NEG_SLOPE * x; }
__device__ inline unsigned short f2h(float x) {
  _Float16 h = (_Float16)x;
  return __builtin_bit_cast(unsigned short, h);
}
__device__ inline float h2f(unsigned short u) {
  return (float)__builtin_bit_cast(_Float16, u);
}

#define GLL16(gp, lp) \
  __builtin_amdgcn_global_load_lds((const __attribute__((address_space(1))) void*)(gp), \
                                   (__attribute__((address_space(3))) void*)(lp), 16, 0, 0)

// ---------------- CSR build ----------------
__global__ __launch_bounds__(256) void k_init_deg(int* __restrict__ deg) {
  int i = blockIdx.x * 256 + threadIdx.x;
  if (i < N_NODES) deg[i] = 1;  // self-loop
}

__global__ __launch_bounds__(256) void k_hist(const int* __restrict__ ei, int* __restrict__ deg) {
  int e = blockIdx.x * 256 + threadIdx.x;
  if (e < E_EDGES) atomicAdd(&deg[ei[E_EDGES + e]], 1);
}

__global__ __launch_bounds__(256) void k_scan1(const int* __restrict__ deg, int* __restrict__ incl,
                                               int* __restrict__ blksum) {
  __shared__ int s[256];
  int tid = threadIdx.x;
  int i = blockIdx.x * 256 + tid;
  int v = (i < N_NODES) ? deg[i] : 0;
  s[tid] = v;
  __syncthreads();
  for (int d = 1; d < 256; d <<= 1) {
    int t = (tid >= d) ? s[tid - d] : 0;
    __syncthreads();
    s[tid] += t;
    __syncthreads();
  }
  if (i < N_NODES) incl[i] = s[tid];
  if (tid == 255) blksum[blockIdx.x] = s[255];
}

__global__ __launch_bounds__(256) void k_scan2(int* __restrict__ blksum, int nblk) {
  __shared__ int s[256];
  int tid = threadIdx.x;
  int v = (tid < nblk) ? blksum[tid] : 0;
  s[tid] = v;
  __syncthreads();
  for (int d = 1; d < 256; d <<= 1) {
    int t = (tid >= d) ? s[tid - d] : 0;
    __syncthreads();
    s[tid] += t;
    __syncthreads();
  }
  if (tid < nblk) blksum[tid] = s[tid] - v;  // exclusive
}

__global__ __launch_bounds__(256) void k_scan3(const int* __restrict__ deg, int* __restrict__ off,
                                               const int* __restrict__ blksum, int* __restrict__ cursor) {
  int i = blockIdx.x * 256 + threadIdx.x;
  if (i < N_NODES) {
    int excl = off[i] - deg[i] + blksum[blockIdx.x];
    off[i] = excl;
    cursor[i] = excl;
  }
  if (i == 0) off[N_NODES] = E_TOT;
}

__global__ __launch_bounds__(256) void k_fill(const int* __restrict__ ei, int* __restrict__ cursor,
                                              int* __restrict__ csr_src) {
  int idx = blockIdx.x * 256 + threadIdx.x;
  if (idx >= E_TOT) return;
  int s, d;
  if (idx < E_EDGES) { s = ei[idx]; d = ei[E_EDGES + idx]; }
  else               { s = idx - E_EDGES; d = s; }
  int pos = atomicAdd(&cursor[d], 1);
  csr_src[pos] = s;
}

// ---------------- fused conversions: x -> fp16 (8-wide), W1/W2/W3 -> fp16 transposed ----------------
__global__ __launch_bounds__(256) void k_cvt_all(const float* __restrict__ x,
                                                 const float* __restrict__ W1,
                                                 const float* __restrict__ W2,
                                                 const float* __restrict__ W3,
                                                 unsigned short* __restrict__ xh,
                                                 unsigned short* __restrict__ Wt1,
                                                 unsigned short* __restrict__ Wt2,
                                                 unsigned short* __restrict__ Wt3) {
  int i = blockIdx.x * 256 + threadIdx.x;
  if (i < XCHUNKS) {
    float4 v0 = *(const float4*)&x[(size_t)i * 8];
    float4 v1 = *(const float4*)&x[(size_t)i * 8 + 4];
    ushort8 o;
    o[0] = f2h(v0.x); o[1] = f2h(v0.y); o[2] = f2h(v0.z); o[3] = f2h(v0.w);
    o[4] = f2h(v1.x); o[5] = f2h(v1.y); o[6] = f2h(v1.z); o[7] = f2h(v1.w);
    *(ushort8*)&xh[(size_t)i * 8] = o;
    return;
  }
  int j = i - XCHUNKS;
  if (j < F_INDIM * HC) {
    int k = j >> 8, n = j & 255;
    Wt1[n * F_INDIM + k] = f2h(W1[j]);
    return;
  }
  j -= F_INDIM * HC;
  if (j < HC * HC) {
    int k = j >> 8, n = j & 255;
    Wt2[n * HC + k] = f2h(W2[j]);
    return;
  }
  j -= HC * HC;
  if (j < HC * HC) {
    int k = j >> 8, n = j & 255;
    Wt3[n * HC + k] = f2h(W3[j]);
  }
}

// ---------------- fp16 MFMA GEMM via global_load_lds + fused attention logits ----------------
// C[M x 256] = A[M x K](f16) * Bt[256 x K](f16)^T, out fp16 dense [N][256].
// m97 structure: 128x128 tile, BK=64, single-buffered 32KB LDS, staging by
// global_load_lds width=16 with PRE-SWIZZLED global source (LDS[r][s] = G[r][s^(r&7)],
// linear LDS dest), read slot (kk*4+qq)^(fl&7) -> <=2-way bank conflicts.
// A must be row-padded so m0+127 is always readable (caller pads workspace).
template<int K>
__global__ __launch_bounds__(256) void k_gemm_f16(const unsigned short* __restrict__ A,
                                                  const unsigned short* __restrict__ Bt,
                                                  unsigned short* __restrict__ C,
                                                  const float* __restrict__ a_src,
                                                  const float* __restrict__ a_dst,
                                                  float* __restrict__ al_s,
                                                  float* __restrict__ al_d) {
  __shared__ unsigned short As[128 * 64];
  __shared__ unsigned short Bs[128 * 64];
  int tid = threadIdx.x;
  int w = tid >> 6, l = tid & 63;
  int wm = w >> 1, wn = w & 1;
  int m0 = blockIdx.x * 128, n0 = blockIdx.y * 128;
  int fl = l & 15, qq = l >> 4;
  int w32 = w * 32;
  int l3 = l >> 3;                       // row-within-8 handled by this lane
  int csw = (l & 7) ^ (l3 & 7);          // pre-swizzled source chunk
  f32x4 acc[4][4] = {};

  for (int k0 = 0; k0 < K; k0 += 64) {
    // stage: 4 waves x 4 calls x (A,B); each call = 8 rows x 128B = 1KB/wave
#pragma unroll
    for (int j = 0; j < 4; ++j) {
      int r = w32 + j * 8 + l3;
      GLL16(&A[(size_t)(m0 + r) * K + k0 + csw * 8], &As[(w32 + j * 8) * 64]);
      GLL16(&Bt[(size_t)(n0 + r) * K + k0 + csw * 8], &Bs[(w32 + j * 8) * 64]);
    }
    __syncthreads();  // drains vmcnt (gll) + barrier
#pragma unroll
    for (int kk = 0; kk < 2; ++kk) {
      f16x8 af[4], bf[4];
      int sl = ((kk * 4 + qq) ^ (fl & 7)) * 8;
#pragma unroll
      for (int f = 0; f < 4; ++f) {
        af[f] = *(const f16x8*)&As[(wm * 64 + f * 16 + fl) * 64 + sl];
        bf[f] = *(const f16x8*)&Bs[(wn * 64 + f * 16 + fl) * 64 + sl];
      }
#pragma unroll
      for (int f = 0; f < 4; ++f)
#pragma unroll
        for (int g = 0; g < 4; ++g)
          acc[f][g] = __builtin_amdgcn_mfma_f32_16x16x32_f16(af[f], bf[g], acc[f][g], 0, 0, 0);
    }
    if (k0 + 64 < K) __syncthreads();  // readers done before next stage overwrites
  }

  // epilogue: D row = (l>>4)*4 + reg, col = l&15; dense fp16 C (guarded)
  int cr = qq * 4;
#pragma unroll
  for (int f = 0; f < 4; ++f) {
    int mrow = m0 + wm * 64 + f * 16 + cr;
#pragma unroll
    for (int r = 0; r < 4; ++r) {
      if (mrow + r < N_NODES) {
#pragma unroll
        for (int g = 0; g < 4; ++g)
          C[(size_t)(mrow + r) * HC + n0 + wn * 64 + g * 16 + fl] = f2h(acc[f][g][r]);
      }
    }
  }
  // fused attention logits for this wave's head
  int head = blockIdx.y * 2 + wn;
  float as_r[4], ad_r[4];
#pragma unroll
  for (int g = 0; g < 4; ++g) {
    as_r[g] = a_src[head * 64 + g * 16 + fl];
    ad_r[g] = a_dst[head * 64 + g * 16 + fl];
  }
#pragma unroll
  for (int f = 0; f < 4; ++f) {
#pragma unroll
    for (int r = 0; r < 4; ++r) {
      float ps = 0.f, pd = 0.f;
#pragma unroll
      for (int g = 0; g < 4; ++g) {
        ps = fmaf(as_r[g], acc[f][g][r], ps);
        pd = fmaf(ad_r[g], acc[f][g][r], pd);
      }
#pragma unroll
      for (int o = 1; o < 16; o <<= 1) { ps += __shfl_xor(ps, o); pd += __shfl_xor(pd, o); }
      if (fl == 0) {
        int row = m0 + wm * 64 + f * 16 + cr + r;
        if (row < N_NODES) {
          al_s[row * 4 + head] = ps;
          al_d[row * 4 + head] = pd;
        }
      }
    }
  }
}

// ---------------- GAT aggregation: persistent, one WAVE per dst node ----------------
// CONCAT=true: writes fp16 [d][256] (next GEMM input, buffer row-padded by caller).
// CONCAT=false: head-mean + bias + relu, then atomicAdd into pooled[batch[d]][64].
template<bool CONCAT>
__global__ __launch_bounds__(256) void k_aggregate(
    const unsigned short* __restrict__ h, const int* __restrict__ off, const int* __restrict__ csr_src,
    const float* __restrict__ al_s, const float* __restrict__ al_d,
    const float* __restrict__ bias, unsigned short* __restrict__ out_h,
    const int* __restrict__ batch, float* __restrict__ pooled) {
  __shared__ float s_p[4][64][4];
  __shared__ int   s_src[4][64];
  int tid = threadIdx.x;
  int wv = tid >> 6;
  int lane = tid & 63;
  int half_id = lane >> 5;
  int c8 = lane & 31;
  int cg8 = c8 << 3;
  int head = c8 >> 3;

  const int NW = AGG_BLOCKS * 4;
  for (int d = blockIdx.x * 4 + wv; d < N_NODES; d += NW) {
    int lo  = off[d];
    int deg = off[d + 1] - lo;

    float4 adv = *(const float4*)&al_d[(size_t)d * 4];

    float z0 = 0.f, z1 = 0.f, z2 = 0.f, z3 = 0.f;
    for (int e = lane; e < deg; e += 64) {
      int s = csr_src[lo + e];
      float4 asv = *(const float4*)&al_s[(size_t)s * 4];
      float p0 = __expf(leakyf(asv.x + adv.x));
      float p1 = __expf(leakyf(asv.y + adv.y));
      float p2 = __expf(leakyf(asv.z + adv.z));
      float p3 = __expf(leakyf(asv.w + adv.w));
      if (e < 64) {
        s_p[wv][e][0] = p0; s_p[wv][e][1] = p1;
        s_p[wv][e][2] = p2; s_p[wv][e][3] = p3;
        s_src[wv][e] = s;
      }
      z0 += p0; z1 += p1; z2 += p2; z3 += p3;
    }
#pragma unroll
    for (int o = 1; o < 64; o <<= 1) {
      z0 += __shfl_xor(z0, o); z1 += __shfl_xor(z1, o);
      z2 += __shfl_xor(z2, o); z3 += __shfl_xor(z3, o);
    }
    float zih = 1.f / ((head == 0 ? z0 : (head == 1 ? z1 : (head == 2 ? z2 : z3))) + 1e-16f);

    int dcap = min(deg, 64);
    float acc[8] = {};
    int e = half_id;
    for (; e + 14 < dcap; e += 16) {
      int sv[8]; float pv[8]; ushort8 hv[8];
#pragma unroll
      for (int q = 0; q < 8; ++q) {
        int ee = e + q * 2;
        sv[q] = s_src[wv][ee];
        pv[q] = s_p[wv][ee][head];
      }
#pragma unroll
      for (int q = 0; q < 8; ++q) hv[q] = *(const ushort8*)&h[(size_t)sv[q] * HC + cg8];
#pragma unroll
      for (int q = 0; q < 8; ++q)
#pragma unroll
        for (int i = 0; i < 8; ++i) acc[i] = fmaf(pv[q], h2f(hv[q][i]), acc[i]);
    }
    for (; e < dcap; e += 2) {
      int s = s_src[wv][e];
      float p = s_p[wv][e][head];
      ushort8 hv = *(const ushort8*)&h[(size_t)s * HC + cg8];
#pragma unroll
      for (int i = 0; i < 8; ++i) acc[i] = fmaf(p, h2f(hv[i]), acc[i]);
    }
    if (deg > 64) {  // rare slow path
      for (int e2 = 64 + half_id; e2 < deg; e2 += 2) {
        int s = csr_src[lo + e2];
        float4 asv = *(const float4*)&al_s[(size_t)s * 4];
        float q0 = __expf(leakyf(asv.x + adv.x));
        float q1 = __expf(leakyf(asv.y + adv.y));
        float q2 = __expf(leakyf(asv.z + adv.z));
        float q3 = __expf(leakyf(asv.w + adv.w));
        float p = head == 0 ? q0 : (head == 1 ? q1 : (head == 2 ? q2 : q3));
        ushort8 hv = *(const ushort8*)&h[(size_t)s * HC + cg8];
#pragma unroll
        for (int i = 0; i < 8; ++i) acc[i] = fmaf(p, h2f(hv[i]), acc[i]);
      }
    }

#pragma unroll
    for (int i = 0; i < 8; ++i) {
      acc[i] *= zih;
      acc[i] += __shfl_xor(acc[i], 32);
    }

    if (CONCAT) {
      if (lane < 32) {
        float4 b0 = *(const float4*)&bias[cg8];
        float4 b1v = *(const float4*)&bias[cg8 + 4];
        ushort8 o;
        o[0] = f2h(fmaxf(acc[0] + b0.x, 0.f));
        o[1] = f2h(fmaxf(acc[1] + b0.y, 0.f));
        o[2] = f2h(fmaxf(acc[2] + b0.z, 0.f));
        o[3] = f2h(fmaxf(acc[3] + b0.w, 0.f));
        o[4] = f2h(fmaxf(acc[4] + b1v.x, 0.f));
        o[5] = f2h(fmaxf(acc[5] + b1v.y, 0.f));
        o[6] = f2h(fmaxf(acc[6] + b1v.z, 0.f));
        o[7] = f2h(fmaxf(acc[7] + b1v.w, 0.f));
        *(ushort8*)&out_h[(size_t)d * HC + cg8] = o;
      }
    } else {
      // head mean: heads live at lanes c8, c8+8, c8+16, c8+24
#pragma unroll
      for (int i = 0; i < 8; ++i) {
        acc[i] += __shfl_xor(acc[i], 8);
        acc[i] += __shfl_xor(acc[i], 16);
      }
      if (lane < 8) {
        int c0 = lane << 3;
        int g = batch[d];
        float* pg = &pooled[(size_t)g * CDIM + c0];
        float4 bb0 = *(const float4*)&bias[c0];
        float4 bb1 = *(const float4*)&bias[c0 + 4];
        atomicAdd(&pg[0], fmaxf(acc[0] * 0.25f + bb0.x, 0.f));
        atomicAdd(&pg[1], fmaxf(acc[1] * 0.25f + bb0.y, 0.f));
        atomicAdd(&pg[2], fmaxf(acc[2] * 0.25f + bb0.z, 0.f));
        atomicAdd(&pg[3], fmaxf(acc[3] * 0.25f + bb0.w, 0.f));
        atomicAdd(&pg[4], fmaxf(acc[4] * 0.25f + bb1.x, 0.f));
        atomicAdd(&pg[5], fmaxf(acc[5] * 0.25f + bb1.y, 0.f));
        atomicAdd(&pg[6], fmaxf(acc[6] * 0.25f + bb1.z, 0.f));
        atomicAdd(&pg[7], fmaxf(acc[7] * 0.25f + bb1.w, 0.f));
      }
    }
  }
}

// ---------------- pool finish: divide by count + final linear ----------------
__device__ inline int lower_bound_i(const int* __restrict__ a, int n, int key) {
  int lo = 0, hi = n;
  while (lo < hi) { int mid = (lo + hi) >> 1; if (a[mid] < key) lo = mid + 1; else hi = mid; }
  return lo;
}

__global__ __launch_bounds__(64) void k_pool_finish(const float* __restrict__ pooled,
                                                    const int* __restrict__ batch,
                                                    const float* __restrict__ Wl,
                                                    const float* __restrict__ bl,
                                                    float* __restrict__ out) {
  int g = blockIdx.x, tid = threadIdx.x;
  int lo = lower_bound_i(batch, N_NODES, g);
  int hi = lower_bound_i(batch, N_NODES, g + 1);
  float cnt = fmaxf((float)(hi - lo), 1.f);
  __shared__ float pl[64];
  pl[tid] = pooled[(size_t)g * CDIM + tid] / cnt;
  __syncthreads();
  if (tid < NCLS) {
    float o = bl[tid];
    for (int cc = 0; cc < CDIM; ++cc)
      o = fmaf(pl[cc], Wl[cc * NCLS + tid], o);
    out[g * NCLS + tid] = o;
  }
}

extern "C" void kernel_launch(void* const* d_in, const int* in_sizes, int n_in,
                              void* d_out, int out_size, void* d_ws, size_t ws_size,
                              hipStream_t stream) {
  const float* x     = (const float*)d_in[0];
  const int*   ei    = (const int*)d_in[1];
  const int*   batch = (const int*)d_in[2];
  const float* W1  = (const float*)d_in[3];
  const float* as1 = (const float*)d_in[4];
  const float* ad1 = (const float*)d_in[5];
  const float* b1  = (const float*)d_in[6];
  const float* W2  = (const float*)d_in[7];
  const float* as2 = (const float*)d_in[8];
  const float* ad2 = (const float*)d_in[9];
  const float* b2  = (const float*)d_in[10];
  const float* W3  = (const float*)d_in[11];
  const float* as3 = (const float*)d_in[12];
  const float* ad3 = (const float*)d_in[13];
  const float* b3  = (const float*)d_in[14];
  const float* Wl  = (const float*)d_in[15];
  const float* bl  = (const float*)d_in[16];
  float* out = (float*)d_out;

  char* ws = (char*)d_ws;
  size_t o = 0;
  auto alloc = [&](size_t bytes) -> void* {
    void* p = ws + o;
    o += (bytes + 255) & ~(size_t)255;
    return p;
  };
  const size_t NPAD = N_NODES + 128;  // row padding so GEMM tiles never read OOB
  unsigned short* hbuf  = (unsigned short*)alloc((size_t)N_NODES * HC * 2);  // GEMM out h (fp16)
  unsigned short* abuf  = (unsigned short*)alloc(NPAD * HC * 2);             // aggregate out (fp16, padded: GEMM input)
  unsigned short* x_h   = (unsigned short*)alloc(NPAD * F_INDIM * 2);        // padded: GEMM input
  unsigned short* Wt1   = (unsigned short*)alloc((size_t)HC * F_INDIM * 2);
  unsigned short* Wt2   = (unsigned short*)alloc((size_t)HC * HC * 2);
  unsigned short* Wt3   = (unsigned short*)alloc((size_t)HC * HC * 2);
  float* al_s  = (float*)alloc((size_t)N_NODES * 4 * 4);
  float* al_d  = (float*)alloc((size_t)N_NODES * 4 * 4);
  float* pooled= (float*)alloc((size_t)NGRAPH * CDIM * 4);
  int*   deg   = (int*)alloc((size_t)N_NODES * 4);
  int*   off   = (int*)alloc((size_t)(N_NODES + 1) * 4);
  int*   cursor= (int*)alloc((size_t)N_NODES * 4);
  int*   blksum= (int*)alloc(1024);
  int*   csr   = (int*)alloc((size_t)E_TOT * 4);

  int nblk = (N_NODES + 255) / 256;  // 196
  k_init_deg<<<nblk, 256, 0, stream>>>(deg);
  k_hist<<<(E_EDGES + 255) / 256, 256, 0, stream>>>(ei, deg);
  k_scan1<<<nblk, 256, 0, stream>>>(deg, off, blksum);
  k_scan2<<<1, 256, 0, stream>>>(blksum, nblk);
  k_scan3<<<nblk, 256, 0, stream>>>(deg, off, blksum, cursor);
  k_fill<<<(E_TOT + 255) / 256, 256, 0, stream>>>(ei, cursor, csr);

  // fused conversions + pooled-accumulator zero
  int cvt_total = XCHUNKS + F_INDIM * HC + 2 * HC * HC;
  k_cvt_all<<<(cvt_total + 255) / 256, 256, 0, stream>>>(x, W1, W2, W3, x_h, Wt1, Wt2, Wt3);
  hipMemsetAsync(pooled, 0, (size_t)NGRAPH * CDIM * 4, stream);

  dim3 ggrid((N_NODES + 127) / 128, HC / 128);  // 391 x 2
  // conv1
  k_gemm_f16<F_INDIM><<<ggrid, 256, 0, stream>>>(x_h, Wt1, hbuf, as1, ad1, al_s, al_d);
  k_aggregate<true><<<AGG_BLOCKS, 256, 0, stream>>>(hbuf, off, csr, al_s, al_d, b1, abuf, nullptr, nullptr);
  // conv2
  k_gemm_f16<HC><<<ggrid, 256, 0, stream>>>(abuf, Wt2, hbuf, as2, ad2, al_s, al_d);
  k_aggregate<true><<<AGG_BLOCKS, 256, 0, stream>>>(hbuf, off, csr, al_s, al_d, b2, abuf, nullptr, nullptr);
  // conv3
  k_gemm_f16<HC><<<ggrid, 256, 0, stream>>>(abuf, Wt3, hbuf, as3, ad3, al_s, al_d);
  k_aggregate<false><<<AGG_BLOCKS, 256, 0, stream>>>(hbuf, off, csr, al_s, al_d, b3, nullptr, batch, pooled);
  // pool finish (divide + final linear)
  k_pool_finish<<<NGRAPH, 64, 0, stream>>>(pooled, batch, Wl, bl, out);
}

// Round 11
// 402.645 us; speedup vs baseline: 1.3286x; 1.3286x over previous
//
#include <hip/hip_runtime.h>

#define N_NODES 50000
#define E_EDGES 800000
#define E_TOT   (E_EDGES + N_NODES)
#define F_INDIM 128
#define NHEAD   4
#define CDIM    64
#define HC      256
#define NGRAPH  512
#define NCLS    10
#define NEG_SLOPE 0.2f
#define AGG_BLOCKS 2048
#define XCHUNKS (N_NODES * F_INDIM / 8)

typedef __attribute__((ext_vector_type(8))) _Float16 f16x8;
typedef __attribute__((ext_vector_type(8))) unsigned short ushort8;
typedef __attribute__((ext_vector_type(4))) float f32x4;

__device__ inline float leakyf(float x) { return x > 0.f ? x : NEG_SLOPE * x; }
__device__ inline unsigned short f2h(float x) {
  _Float16 h = (_Float16)x;
  return __builtin_bit_cast(unsigned short, h);
}
__device__ inline float h2f(unsigned short u) {
  return (float)__builtin_bit_cast(_Float16, u);
}

#define GLL16(gp, lp) \
  __builtin_amdgcn_global_load_lds((const __attribute__((address_space(1))) void*)(gp), \
                                   (__attribute__((address_space(3))) void*)(lp), 16, 0, 0)

// ---------------- CSR build ----------------
__global__ __launch_bounds__(256) void k_init_deg(int* __restrict__ deg) {
  int i = blockIdx.x * 256 + threadIdx.x;
  if (i < N_NODES) deg[i] = 1;  // self-loop
}

__global__ __launch_bounds__(256) void k_hist(const int* __restrict__ ei, int* __restrict__ deg) {
  int e = blockIdx.x * 256 + threadIdx.x;
  if (e < E_EDGES) atomicAdd(&deg[ei[E_EDGES + e]], 1);
}

__global__ __launch_bounds__(256) void k_scan1(const int* __restrict__ deg, int* __restrict__ incl,
                                               int* __restrict__ blksum) {
  __shared__ int s[256];
  int tid = threadIdx.x;
  int i = blockIdx.x * 256 + tid;
  int v = (i < N_NODES) ? deg[i] : 0;
  s[tid] = v;
  __syncthreads();
  for (int d = 1; d < 256; d <<= 1) {
    int t = (tid >= d) ? s[tid - d] : 0;
    __syncthreads();
    s[tid] += t;
    __syncthreads();
  }
  if (i < N_NODES) incl[i] = s[tid];
  if (tid == 255) blksum[blockIdx.x] = s[255];
}

__global__ __launch_bounds__(256) void k_scan2(int* __restrict__ blksum, int nblk) {
  __shared__ int s[256];
  int tid = threadIdx.x;
  int v = (tid < nblk) ? blksum[tid] : 0;
  s[tid] = v;
  __syncthreads();
  for (int d = 1; d < 256; d <<= 1) {
    int t = (tid >= d) ? s[tid - d] : 0;
    __syncthreads();
    s[tid] += t;
    __syncthreads();
  }
  if (tid < nblk) blksum[tid] = s[tid] - v;  // exclusive
}

__global__ __launch_bounds__(256) void k_scan3(const int* __restrict__ deg, int* __restrict__ off,
                                               const int* __restrict__ blksum, int* __restrict__ cursor) {
  int i = blockIdx.x * 256 + threadIdx.x;
  if (i < N_NODES) {
    int excl = off[i] - deg[i] + blksum[blockIdx.x];
    off[i] = excl;
    cursor[i] = excl;
  }
  if (i == 0) off[N_NODES] = E_TOT;
}

__global__ __launch_bounds__(256) void k_fill(const int* __restrict__ ei, int* __restrict__ cursor,
                                              int* __restrict__ csr_src) {
  int idx = blockIdx.x * 256 + threadIdx.x;
  if (idx >= E_TOT) return;
  int s, d;
  if (idx < E_EDGES) { s = ei[idx]; d = ei[E_EDGES + idx]; }
  else               { s = idx - E_EDGES; d = s; }
  int pos = atomicAdd(&cursor[d], 1);
  csr_src[pos] = s;
}

// ---------------- fused conversions: x -> fp16 (8-wide), W1/W2/W3 -> fp16 transposed ----------------
__global__ __launch_bounds__(256) void k_cvt_all(const float* __restrict__ x,
                                                 const float* __restrict__ W1,
                                                 const float* __restrict__ W2,
                                                 const float* __restrict__ W3,
                                                 unsigned short* __restrict__ xh,
                                                 unsigned short* __restrict__ Wt1,
                                                 unsigned short* __restrict__ Wt2,
                                                 unsigned short* __restrict__ Wt3) {
  int i = blockIdx.x * 256 + threadIdx.x;
  if (i < XCHUNKS) {
    float4 v0 = *(const float4*)&x[(size_t)i * 8];
    float4 v1 = *(const float4*)&x[(size_t)i * 8 + 4];
    ushort8 o;
    o[0] = f2h(v0.x); o[1] = f2h(v0.y); o[2] = f2h(v0.z); o[3] = f2h(v0.w);
    o[4] = f2h(v1.x); o[5] = f2h(v1.y); o[6] = f2h(v1.z); o[7] = f2h(v1.w);
    *(ushort8*)&xh[(size_t)i * 8] = o;
    return;
  }
  int j = i - XCHUNKS;
  if (j < F_INDIM * HC) {
    int k = j >> 8, n = j & 255;
    Wt1[n * F_INDIM + k] = f2h(W1[j]);
    return;
  }
  j -= F_INDIM * HC;
  if (j < HC * HC) {
    int k = j >> 8, n = j & 255;
    Wt2[n * HC + k] = f2h(W2[j]);
    return;
  }
  j -= HC * HC;
  if (j < HC * HC) {
    int k = j >> 8, n = j & 255;
    Wt3[n * HC + k] = f2h(W3[j]);
  }
}

// ---------------- fp16 MFMA GEMM via global_load_lds + fused attention logits ----------------
// (round-10 kernel, confirmed ~15 us/GEMM faster than register staging)
// C[M x 256] = A[M x K](f16) * Bt[256 x K](f16)^T, out fp16 dense [N][256].
// 128x128 tile, BK=64, single-buffered 32KB LDS, global_load_lds width=16 with
// PRE-SWIZZLED global source (LDS[r][s] = G[r][s^(r&7)], linear LDS dest),
// read slot (kk*4+qq)^(fl&7) -> <=2-way bank conflicts.
// A must be row-padded so m0+127 is always readable (caller pads workspace).
template<int K>
__global__ __launch_bounds__(256) void k_gemm_f16(const unsigned short* __restrict__ A,
                                                  const unsigned short* __restrict__ Bt,
                                                  unsigned short* __restrict__ C,
                                                  const float* __restrict__ a_src,
                                                  const float* __restrict__ a_dst,
                                                  float* __restrict__ al_s,
                                                  float* __restrict__ al_d) {
  __shared__ unsigned short As[128 * 64];
  __shared__ unsigned short Bs[128 * 64];
  int tid = threadIdx.x;
  int w = tid >> 6, l = tid & 63;
  int wm = w >> 1, wn = w & 1;
  int m0 = blockIdx.x * 128, n0 = blockIdx.y * 128;
  int fl = l & 15, qq = l >> 4;
  int w32 = w * 32;
  int l3 = l >> 3;                       // row-within-8 handled by this lane
  int csw = (l & 7) ^ (l3 & 7);          // pre-swizzled source chunk
  f32x4 acc[4][4] = {};

  for (int k0 = 0; k0 < K; k0 += 64) {
#pragma unroll
    for (int j = 0; j < 4; ++j) {
      int r = w32 + j * 8 + l3;
      GLL16(&A[(size_t)(m0 + r) * K + k0 + csw * 8], &As[(w32 + j * 8) * 64]);
      GLL16(&Bt[(size_t)(n0 + r) * K + k0 + csw * 8], &Bs[(w32 + j * 8) * 64]);
    }
    __syncthreads();  // drains vmcnt (gll) + barrier
#pragma unroll
    for (int kk = 0; kk < 2; ++kk) {
      f16x8 af[4], bf[4];
      int sl = ((kk * 4 + qq) ^ (fl & 7)) * 8;
#pragma unroll
      for (int f = 0; f < 4; ++f) {
        af[f] = *(const f16x8*)&As[(wm * 64 + f * 16 + fl) * 64 + sl];
        bf[f] = *(const f16x8*)&Bs[(wn * 64 + f * 16 + fl) * 64 + sl];
      }
#pragma unroll
      for (int f = 0; f < 4; ++f)
#pragma unroll
        for (int g = 0; g < 4; ++g)
          acc[f][g] = __builtin_amdgcn_mfma_f32_16x16x32_f16(af[f], bf[g], acc[f][g], 0, 0, 0);
    }
    if (k0 + 64 < K) __syncthreads();  // readers done before next stage overwrites
  }

  // epilogue: D row = (l>>4)*4 + reg, col = l&15; dense fp16 C (guarded)
  int cr = qq * 4;
#pragma unroll
  for (int f = 0; f < 4; ++f) {
    int mrow = m0 + wm * 64 + f * 16 + cr;
#pragma unroll
    for (int r = 0; r < 4; ++r) {
      if (mrow + r < N_NODES) {
#pragma unroll
        for (int g = 0; g < 4; ++g)
          C[(size_t)(mrow + r) * HC + n0 + wn * 64 + g * 16 + fl] = f2h(acc[f][g][r]);
      }
    }
  }
  // fused attention logits for this wave's head
  int head = blockIdx.y * 2 + wn;
  float as_r[4], ad_r[4];
#pragma unroll
  for (int g = 0; g < 4; ++g) {
    as_r[g] = a_src[head * 64 + g * 16 + fl];
    ad_r[g] = a_dst[head * 64 + g * 16 + fl];
  }
#pragma unroll
  for (int f = 0; f < 4; ++f) {
#pragma unroll
    for (int r = 0; r < 4; ++r) {
      float ps = 0.f, pd = 0.f;
#pragma unroll
      for (int g = 0; g < 4; ++g) {
        ps = fmaf(as_r[g], acc[f][g][r], ps);
        pd = fmaf(ad_r[g], acc[f][g][r], pd);
      }
#pragma unroll
      for (int o = 1; o < 16; o <<= 1) { ps += __shfl_xor(ps, o); pd += __shfl_xor(pd, o); }
      if (fl == 0) {
        int row = m0 + wm * 64 + f * 16 + cr + r;
        if (row < N_NODES) {
          al_s[row * 4 + head] = ps;
          al_d[row * 4 + head] = pd;
        }
      }
    }
  }
}

// ---------------- GAT aggregation: persistent, one WAVE per dst node ----------------
// (round-7/9 kernel: 76 us / 208 MB fetch — at the per-XCD compulsory-fetch wall)
// CONCAT=true: writes fp16 [d][256]; CONCAT=false: head-mean -> f32 [d][64].
template<bool CONCAT>
__global__ __launch_bounds__(256) void k_aggregate(
    const unsigned short* __restrict__ h, const int* __restrict__ off, const int* __restrict__ csr_src,
    const float* __restrict__ al_s, const float* __restrict__ al_d,
    const float* __restrict__ bias, unsigned short* __restrict__ out_h, float* __restrict__ out_f) {
  __shared__ float s_p[4][64][4];
  __shared__ int   s_src[4][64];
  int tid = threadIdx.x;
  int wv = tid >> 6;
  int lane = tid & 63;
  int half_id = lane >> 5;
  int c8 = lane & 31;
  int cg8 = c8 << 3;
  int head = c8 >> 3;

  const int NW = AGG_BLOCKS * 4;
  for (int d = blockIdx.x * 4 + wv; d < N_NODES; d += NW) {
    int lo  = off[d];
    int deg = off[d + 1] - lo;

    float4 adv = *(const float4*)&al_d[(size_t)d * 4];

    float z0 = 0.f, z1 = 0.f, z2 = 0.f, z3 = 0.f;
    for (int e = lane; e < deg; e += 64) {
      int s = csr_src[lo + e];
      float4 asv = *(const float4*)&al_s[(size_t)s * 4];
      float p0 = __expf(leakyf(asv.x + adv.x));
      float p1 = __expf(leakyf(asv.y + adv.y));
      float p2 = __expf(leakyf(asv.z + adv.z));
      float p3 = __expf(leakyf(asv.w + adv.w));
      if (e < 64) {
        s_p[wv][e][0] = p0; s_p[wv][e][1] = p1;
        s_p[wv][e][2] = p2; s_p[wv][e][3] = p3;
        s_src[wv][e] = s;
      }
      z0 += p0; z1 += p1; z2 += p2; z3 += p3;
    }
#pragma unroll
    for (int o = 1; o < 64; o <<= 1) {
      z0 += __shfl_xor(z0, o); z1 += __shfl_xor(z1, o);
      z2 += __shfl_xor(z2, o); z3 += __shfl_xor(z3, o);
    }
    float zih = 1.f / ((head == 0 ? z0 : (head == 1 ? z1 : (head == 2 ? z2 : z3))) + 1e-16f);

    int dcap = min(deg, 64);
    float acc[8] = {};
    int e = half_id;
    for (; e + 14 < dcap; e += 16) {
      int sv[8]; float pv[8]; ushort8 hv[8];
#pragma unroll
      for (int q = 0; q < 8; ++q) {
        int ee = e + q * 2;
        sv[q] = s_src[wv][ee];
        pv[q] = s_p[wv][ee][head];
      }
#pragma unroll
      for (int q = 0; q < 8; ++q) hv[q] = *(const ushort8*)&h[(size_t)sv[q] * HC + cg8];
#pragma unroll
      for (int q = 0; q < 8; ++q)
#pragma unroll
        for (int i = 0; i < 8; ++i) acc[i] = fmaf(pv[q], h2f(hv[q][i]), acc[i]);
    }
    for (; e < dcap; e += 2) {
      int s = s_src[wv][e];
      float p = s_p[wv][e][head];
      ushort8 hv = *(const ushort8*)&h[(size_t)s * HC + cg8];
#pragma unroll
      for (int i = 0; i < 8; ++i) acc[i] = fmaf(p, h2f(hv[i]), acc[i]);
    }
    if (deg > 64) {  // rare slow path
      for (int e2 = 64 + half_id; e2 < deg; e2 += 2) {
        int s = csr_src[lo + e2];
        float4 asv = *(const float4*)&al_s[(size_t)s * 4];
        float q0 = __expf(leakyf(asv.x + adv.x));
        float q1 = __expf(leakyf(asv.y + adv.y));
        float q2 = __expf(leakyf(asv.z + adv.z));
        float q3 = __expf(leakyf(asv.w + adv.w));
        float p = head == 0 ? q0 : (head == 1 ? q1 : (head == 2 ? q2 : q3));
        ushort8 hv = *(const ushort8*)&h[(size_t)s * HC + cg8];
#pragma unroll
        for (int i = 0; i < 8; ++i) acc[i] = fmaf(p, h2f(hv[i]), acc[i]);
      }
    }

#pragma unroll
    for (int i = 0; i < 8; ++i) {
      acc[i] *= zih;
      acc[i] += __shfl_xor(acc[i], 32);
    }

    if (CONCAT) {
      if (lane < 32) {
        float4 b0 = *(const float4*)&bias[cg8];
        float4 b1v = *(const float4*)&bias[cg8 + 4];
        ushort8 o;
        o[0] = f2h(fmaxf(acc[0] + b0.x, 0.f));
        o[1] = f2h(fmaxf(acc[1] + b0.y, 0.f));
        o[2] = f2h(fmaxf(acc[2] + b0.z, 0.f));
        o[3] = f2h(fmaxf(acc[3] + b0.w, 0.f));
        o[4] = f2h(fmaxf(acc[4] + b1v.x, 0.f));
        o[5] = f2h(fmaxf(acc[5] + b1v.y, 0.f));
        o[6] = f2h(fmaxf(acc[6] + b1v.z, 0.f));
        o[7] = f2h(fmaxf(acc[7] + b1v.w, 0.f));
        *(ushort8*)&out_h[(size_t)d * HC + cg8] = o;
      }
    } else {
      // head mean: heads live at lanes c8, c8+8, c8+16, c8+24
#pragma unroll
      for (int i = 0; i < 8; ++i) {
        acc[i] += __shfl_xor(acc[i], 8);
        acc[i] += __shfl_xor(acc[i], 16);
      }
      if (lane < 8) {
        int c0 = lane << 3;
        float4 bb0 = *(const float4*)&bias[c0];
        float4 bb1 = *(const float4*)&bias[c0 + 4];
        float4 v0, v1;
        v0.x = fmaxf(acc[0] * 0.25f + bb0.x, 0.f);
        v0.y = fmaxf(acc[1] * 0.25f + bb0.y, 0.f);
        v0.z = fmaxf(acc[2] * 0.25f + bb0.z, 0.f);
        v0.w = fmaxf(acc[3] * 0.25f + bb0.w, 0.f);
        v1.x = fmaxf(acc[4] * 0.25f + bb1.x, 0.f);
        v1.y = fmaxf(acc[5] * 0.25f + bb1.y, 0.f);
        v1.z = fmaxf(acc[6] * 0.25f + bb1.z, 0.f);
        v1.w = fmaxf(acc[7] * 0.25f + bb1.w, 0.f);
        *(float4*)&out_f[(size_t)d * CDIM + c0] = v0;
        *(float4*)&out_f[(size_t)d * CDIM + c0 + 4] = v1;
      }
    }
  }
}

// ---------------- global mean pool + final linear ----------------
__device__ inline int lower_bound_i(const int* __restrict__ a, int n, int key) {
  int lo = 0, hi = n;
  while (lo < hi) { int mid = (lo + hi) >> 1; if (a[mid] < key) lo = mid + 1; else hi = mid; }
  return lo;
}

__global__ __launch_bounds__(256) void k_pool(const float* __restrict__ x, const int* __restrict__ batch,
                                              const float* __restrict__ Wl, const float* __restrict__ bl,
                                              float* __restrict__ out) {
  int g = blockIdx.x, tid = threadIdx.x;
  int lo = lower_bound_i(batch, N_NODES, g);
  int hi = lower_bound_i(batch, N_NODES, g + 1);
  int c = tid & 63, sl = tid >> 6;
  float acc = 0.f;
  for (int n = lo + sl; n < hi; n += 4)
    acc += x[(size_t)n * CDIM + c];
  __shared__ float s[256];
  __shared__ float pooled[64];
  s[tid] = acc;
  __syncthreads();
  if (tid < 64) {
    float cnt = fmaxf((float)(hi - lo), 1.f);
    pooled[tid] = (s[tid] + s[tid + 64] + s[tid + 128] + s[tid + 192]) / cnt;
  }
  __syncthreads();
  if (tid < NCLS) {
    float o = bl[tid];
    for (int cc = 0; cc < CDIM; ++cc)
      o = fmaf(pooled[cc], Wl[cc * NCLS + tid], o);
    out[g * NCLS + tid] = o;
  }
}

extern "C" void kernel_launch(void* const* d_in, const int* in_sizes, int n_in,
                              void* d_out, int out_size, void* d_ws, size_t ws_size,
                              hipStream_t stream) {
  const float* x     = (const float*)d_in[0];
  const int*   ei    = (const int*)d_in[1];
  const int*   batch = (const int*)d_in[2];
  const float* W1  = (const float*)d_in[3];
  const float* as1 = (const float*)d_in[4];
  const float* ad1 = (const float*)d_in[5];
  const float* b1  = (const float*)d_in[6];
  const float* W2  = (const float*)d_in[7];
  const float* as2 = (const float*)d_in[8];
  const float* ad2 = (const float*)d_in[9];
  const float* b2  = (const float*)d_in[10];
  const float* W3  = (const float*)d_in[11];
  const float* as3 = (const float*)d_in[12];
  const float* ad3 = (const float*)d_in[13];
  const float* b3  = (const float*)d_in[14];
  const float* Wl  = (const float*)d_in[15];
  const float* bl  = (const float*)d_in[16];
  float* out = (float*)d_out;

  char* ws = (char*)d_ws;
  size_t o = 0;
  auto alloc = [&](size_t bytes) -> void* {
    void* p = ws + o;
    o += (bytes + 255) & ~(size_t)255;
    return p;
  };
  const size_t NPAD = N_NODES + 128;  // row padding so GEMM tiles never read OOB
  unsigned short* hbuf  = (unsigned short*)alloc((size_t)N_NODES * HC * 2);  // GEMM out h (fp16)
  unsigned short* abuf  = (unsigned short*)alloc(NPAD * HC * 2);             // aggregate out (fp16, padded: GEMM input)
  float*          bufC  = (float*)alloc((size_t)N_NODES * CDIM * 4);         // conv3 out (f32)
  unsigned short* x_h   = (unsigned short*)alloc(NPAD * F_INDIM * 2);        // padded: GEMM input
  unsigned short* Wt1   = (unsigned short*)alloc((size_t)HC * F_INDIM * 2);
  unsigned short* Wt2   = (unsigned short*)alloc((size_t)HC * HC * 2);
  unsigned short* Wt3   = (unsigned short*)alloc((size_t)HC * HC * 2);
  float* al_s  = (float*)alloc((size_t)N_NODES * 4 * 4);
  float* al_d  = (float*)alloc((size_t)N_NODES * 4 * 4);
  int*   deg   = (int*)alloc((size_t)N_NODES * 4);
  int*   off   = (int*)alloc((size_t)(N_NODES + 1) * 4);
  int*   cursor= (int*)alloc((size_t)N_NODES * 4);
  int*   blksum= (int*)alloc(1024);
  int*   csr   = (int*)alloc((size_t)E_TOT * 4);

  int nblk = (N_NODES + 255) / 256;  // 196
  k_init_deg<<<nblk, 256, 0, stream>>>(deg);
  k_hist<<<(E_EDGES + 255) / 256, 256, 0, stream>>>(ei, deg);
  k_scan1<<<nblk, 256, 0, stream>>>(deg, off, blksum);
  k_scan2<<<1, 256, 0, stream>>>(blksum, nblk);
  k_scan3<<<nblk, 256, 0, stream>>>(deg, off, blksum, cursor);
  k_fill<<<(E_TOT + 255) / 256, 256, 0, stream>>>(ei, cursor, csr);

  // fused conversions
  int cvt_total = XCHUNKS + F_INDIM * HC + 2 * HC * HC;
  k_cvt_all<<<(cvt_total + 255) / 256, 256, 0, stream>>>(x, W1, W2, W3, x_h, Wt1, Wt2, Wt3);

  dim3 ggrid((N_NODES + 127) / 128, HC / 128);  // 391 x 2
  // conv1
  k_gemm_f16<F_INDIM><<<ggrid, 256, 0, stream>>>(x_h, Wt1, hbuf, as1, ad1, al_s, al_d);
  k_aggregate<true><<<AGG_BLOCKS, 256, 0, stream>>>(hbuf, off, csr, al_s, al_d, b1, abuf, nullptr);
  // conv2
  k_gemm_f16<HC><<<ggrid, 256, 0, stream>>>(abuf, Wt2, hbuf, as2, ad2, al_s, al_d);
  k_aggregate<true><<<AGG_BLOCKS, 256, 0, stream>>>(hbuf, off, csr, al_s, al_d, b2, abuf, nullptr);
  // conv3
  k_gemm_f16<HC><<<ggrid, 256, 0, stream>>>(abuf, Wt3, hbuf, as3, ad3, al_s, al_d);
  k_aggregate<false><<<AGG_BLOCKS, 256, 0, stream>>>(hbuf, off, csr, al_s, al_d, b3, nullptr, bufC);
  // pool + linear
  k_pool<<<NGRAPH, 256, 0, stream>>>(bufC, batch, Wl, bl, out);
}